// Round 2
// baseline (295.890 us; speedup 1.0000x reference)
//
#include <hip/hip_runtime.h>
#include <hip/hip_bf16.h>

#define N_TOK 8192
#define DIN   1024
#define DOUT  1024
#define NE    8
#define BM    128
#define BN    128
#define BK    32
#define KTOT  (NE * DIN)          // 8192
#define NSTEP (KTOT / BK)         // 256

typedef __attribute__((ext_vector_type(4))) float f32x4;
typedef __attribute__((ext_vector_type(8))) short short8;
typedef unsigned int u32;

__device__ __forceinline__ ushort f2bf(float f) {
    u32 u = __float_as_uint(f);
    u32 r = (u + 0x7fffu + ((u >> 16) & 1u)) >> 16;   // round-to-nearest-even
    return (ushort)r;
}

__device__ __forceinline__ void gload_lds16(const void* gp, void* lp) {
    __builtin_amdgcn_global_load_lds(
        (const __attribute__((address_space(1))) u32*)gp,
        (__attribute__((address_space(3))) u32*)lp, 16, 0, 0);
}

// ---------------- gating: softmax(x @ Wg + bg) -> g [N_TOK][NE] (f32) -----------
__global__ void gate_kernel(const float* __restrict__ x, const float* __restrict__ Wg,
                            const float* __restrict__ bg, float* __restrict__ g) {
    int w = threadIdx.x >> 6, lane = threadIdx.x & 63;
    int n = blockIdx.x * 4 + w;
    const float* xr = x + (size_t)n * DIN;
    float p[NE];
#pragma unroll
    for (int e = 0; e < NE; ++e) p[e] = 0.f;
    for (int i = lane; i < DIN; i += 64) {
        float xv = xr[i];
        const float* wr_ = Wg + i * NE;
#pragma unroll
        for (int e = 0; e < NE; ++e) p[e] = fmaf(xv, wr_[e], p[e]);
    }
#pragma unroll
    for (int off = 32; off > 0; off >>= 1) {
#pragma unroll
        for (int e = 0; e < NE; ++e) p[e] += __shfl_down(p[e], off);
    }
    if (lane == 0) {
        float l2[NE], m = -1e30f;
#pragma unroll
        for (int e = 0; e < NE; ++e) { l2[e] = p[e] + bg[e]; m = fmaxf(m, l2[e]); }
        float s = 0.f;
#pragma unroll
        for (int e = 0; e < NE; ++e) { l2[e] = expf(l2[e] - m); s += l2[e]; }
        float inv = 1.f / s;
#pragma unroll
        for (int e = 0; e < NE; ++e) g[n * NE + e] = l2[e] * inv;
    }
}

// ---------------- x (f32) -> xb (bf16), 4 elems/thread --------------------------
__global__ void cvt_x_kernel(const float* __restrict__ x, ushort* __restrict__ xb) {
    int idx = blockIdx.x * 256 + threadIdx.x;
    float4 v = ((const float4*)x)[idx];
    ushort4 o = make_ushort4(f2bf(v.x), f2bf(v.y), f2bf(v.z), f2bf(v.w));
    ((ushort4*)xb)[idx] = o;
}

// ---------------- We [8192][1024] f32 -> BT [1024][8192] bf16 (transposed) ------
__global__ void transpose_w_kernel(const float* __restrict__ We, ushort* __restrict__ BT) {
    __shared__ float tile[64][65];
    int kb = blockIdx.x * 64, ob = blockIdx.y * 64;
    int t = threadIdx.x;
#pragma unroll
    for (int ph = 0; ph < 16; ++ph) {
        int idx = ph * 256 + t;
        int r = idx >> 6, c = idx & 63;
        tile[r][c] = We[(size_t)(kb + r) * DOUT + ob + c];
    }
    __syncthreads();
#pragma unroll
    for (int ph = 0; ph < 16; ++ph) {
        int idx = ph * 256 + t;
        int r = idx >> 6, c = idx & 63;
        BT[(size_t)(ob + r) * KTOT + kb + c] = f2bf(tile[c][r]);
    }
}

// ---------------- fused MoE GEMM: out = sum_e g_e * (x @ We_e) + sum_e g_e*be_e --
// accP: f32 accumulator for current expert (MFMA C/D).
// accB: bf16-packed running gate-weighted sum over experts 0..6 (2 rows per u32).
// Expert 7 stays in accP at loop end and folds in f32 in the epilogue.
__global__ __launch_bounds__(256, 3) void moe_gemm(
    const ushort* __restrict__ xb,   // [8192][1024] bf16
    const ushort* __restrict__ BT,   // [1024][8192] bf16 (o-major, k-minor)
    const float*  __restrict__ g,    // [8192][8]
    const float*  __restrict__ be,   // [8][1024]
    float*        __restrict__ out)  // [8192][1024]
{
    __shared__ __align__(16) ushort Alds[2][BM][BK];
    __shared__ __align__(16) ushort Blds[2][BN][BK];

    int bid = blockIdx.x;
    // XCD-local mapping: dispatch round-robins XCDs on bid, so bid&7 == XCD.
    // Each XCD owns ONE 128-col B panel (2MB -> fits 4MB private L2); A streams
    // once from HBM and is shared across XCDs via L3.
    int colb = bid & 7;
    int rowb = bid >> 3;
    int brow = rowb * BM, bcol = colb * BN;

    int t = threadIdx.x;
    int w = t >> 6, lane = t & 63;
    int wr = (w >> 1) * 64, wc = (w & 1) * 64;   // 2x2 wave grid, 64x64 per wave

    f32x4 accP[4][4];
    u32   accB[4][4][2];   // [m][n][jpair]; lo16 = j even, hi16 = j odd (bf16)
#pragma unroll
    for (int m = 0; m < 4; ++m)
#pragma unroll
        for (int n = 0; n < 4; ++n) {
            accP[m][n] = (f32x4){0.f, 0.f, 0.f, 0.f};
            accB[m][n][0] = 0u; accB[m][n][1] = 0u;
        }

    // per-lane staging geometry: chunk q = (rr*4+w)*64 + lane; 8 elems each
    // row = q>>2, col = (q&3)*8 ; lds byte base (wave-uniform) = (rr*4+w)*1024
    int srow[2], scol[2];
#pragma unroll
    for (int rr = 0; rr < 2; ++rr) {
        int q = (rr * 4 + w) * 64 + lane;
        srow[rr] = q >> 2;
        scol[rr] = (q & 3) * 8;
    }

    // stage kt = 0
#pragma unroll
    for (int rr = 0; rr < 2; ++rr) {
        gload_lds16(xb + (size_t)(brow + srow[rr]) * DIN + scol[rr],
                    (char*)&Alds[0][0][0] + (rr * 4 + w) * 1024);
        gload_lds16(BT + (size_t)(bcol + srow[rr]) * KTOT + scol[rr],
                    (char*)&Blds[0][0][0] + (rr * 4 + w) * 1024);
    }
    __syncthreads();

    int cur = 0;
    int ro = lane & 15, ko = (lane >> 4) * 8;
    int jrow = (lane >> 4) * 4;   // first of the 4 C-rows this lane holds per m

    for (int kt = 0; kt < NSTEP; ++kt) {
        if (kt < NSTEP - 1) {
            int k2 = (kt + 1) * BK;           // global k
            int ka = k2 & (DIN - 1);          // within-expert k for A
#pragma unroll
            for (int rr = 0; rr < 2; ++rr) {
                gload_lds16(xb + (size_t)(brow + srow[rr]) * DIN + ka + scol[rr],
                            (char*)&Alds[cur ^ 1][0][0] + (rr * 4 + w) * 1024);
                gload_lds16(BT + (size_t)(bcol + srow[rr]) * KTOT + k2 + scol[rr],
                            (char*)&Blds[cur ^ 1][0][0] + (rr * 4 + w) * 1024);
            }
        }

        short8 af[4], bfr[4];
#pragma unroll
        for (int m = 0; m < 4; ++m)
            af[m] = *(const short8*)&Alds[cur][wr + m * 16 + ro][ko];
#pragma unroll
        for (int n = 0; n < 4; ++n)
            bfr[n] = *(const short8*)&Blds[cur][wc + n * 16 + ro][ko];
#pragma unroll
        for (int m = 0; m < 4; ++m)
#pragma unroll
            for (int n = 0; n < 4; ++n)
                accP[m][n] = __builtin_amdgcn_mfma_f32_16x16x32_bf16(
                    af[m], bfr[n], accP[m][n], 0, 0, 0);

        // expert boundary (not the last): fold gate-weighted partial into bf16 accB
        if ((kt & 31) == 31 && kt != NSTEP - 1) {
            int e = kt >> 5;
#pragma unroll
            for (int m = 0; m < 4; ++m) {
                int rbase = brow + wr + m * 16 + jrow;
                float g0 = g[(rbase + 0) * NE + e];
                float g1 = g[(rbase + 1) * NE + e];
                float g2 = g[(rbase + 2) * NE + e];
                float g3 = g[(rbase + 3) * NE + e];
#pragma unroll
                for (int n = 0; n < 4; ++n) {
                    u32 p0 = accB[m][n][0];
                    float lo0 = __uint_as_float(p0 << 16)          + g0 * accP[m][n][0];
                    float hi0 = __uint_as_float(p0 & 0xffff0000u)  + g1 * accP[m][n][1];
                    accB[m][n][0] = (u32)f2bf(lo0) | ((u32)f2bf(hi0) << 16);
                    u32 p1 = accB[m][n][1];
                    float lo1 = __uint_as_float(p1 << 16)          + g2 * accP[m][n][2];
                    float hi1 = __uint_as_float(p1 & 0xffff0000u)  + g3 * accP[m][n][3];
                    accB[m][n][1] = (u32)f2bf(lo1) | ((u32)f2bf(hi1) << 16);
                    accP[m][n] = (f32x4){0.f, 0.f, 0.f, 0.f};
                }
            }
        }
        __syncthreads();
        cur ^= 1;
    }

    // epilogue: out = unpack(accB) + g7*accP + sum_e g_e*be_e
#pragma unroll
    for (int m = 0; m < 4; ++m) {
#pragma unroll
        for (int j = 0; j < 4; ++j) {
            int grow = brow + wr + m * 16 + jrow + j;
            const float* gr = g + grow * NE;
            float g8[NE];
#pragma unroll
            for (int e = 0; e < NE; ++e) g8[e] = gr[e];
#pragma unroll
            for (int n = 0; n < 4; ++n) {
                int col = bcol + wc + n * 16 + (lane & 15);
                float bias = 0.f;
#pragma unroll
                for (int e = 0; e < NE; ++e) bias = fmaf(g8[e], be[e * DOUT + col], bias);
                u32 p = accB[m][n][j >> 1];
                float base = __uint_as_float((j & 1) ? (p & 0xffff0000u) : (p << 16));
                out[(size_t)grow * DOUT + col] = base + g8[7] * accP[m][n][j] + bias;
            }
        }
    }
}

extern "C" void kernel_launch(void* const* d_in, const int* in_sizes, int n_in,
                              void* d_out, int out_size, void* d_ws, size_t ws_size,
                              hipStream_t stream) {
    const float* x  = (const float*)d_in[0];
    const float* We = (const float*)d_in[1];
    const float* be = (const float*)d_in[2];
    const float* Wg = (const float*)d_in[3];
    const float* bg = (const float*)d_in[4];
    float* out = (float*)d_out;

    char* ws = (char*)d_ws;
    float*  gbuf = (float*)ws;                                       // 256 KB
    ushort* xb   = (ushort*)(ws + (size_t)256 * 1024);               // 16 MB
    ushort* BT   = (ushort*)(ws + (size_t)256 * 1024 + (size_t)N_TOK * DIN * 2); // 16 MB

    gate_kernel<<<N_TOK / 4, 256, 0, stream>>>(x, Wg, bg, gbuf);
    cvt_x_kernel<<<(N_TOK * DIN / 4) / 256, 256, 0, stream>>>(x, xb);
    transpose_w_kernel<<<dim3(KTOT / 64, DOUT / 64), 256, 0, stream>>>(We, BT);
    moe_gemm<<<(N_TOK / BM) * (DOUT / BN), 256, 0, stream>>>(xb, BT, gbuf, be, out);
}

// Round 3
// 245.887 us; speedup vs baseline: 1.2034x; 1.2034x over previous
//
#include <hip/hip_runtime.h>
#include <hip/hip_bf16.h>

#define N_TOK 8192
#define DIN   1024
#define DOUT  1024
#define NE    8
#define KTOT  (NE * DIN)          // 8192
#define BM    256
#define BN    128
#define BK    64
#define NT    (KTOT / BK)         // 128 K-tiles

typedef __attribute__((ext_vector_type(4))) float f32x4;
typedef __attribute__((ext_vector_type(8))) short short8;
typedef unsigned int u32;

__device__ __forceinline__ ushort f2bf(float f) {
    u32 u = __float_as_uint(f);
    u32 r = (u + 0x7fffu + ((u >> 16) & 1u)) >> 16;   // round-to-nearest-even
    return (ushort)r;
}

__device__ __forceinline__ void gload_lds16(const void* gp, void* lp) {
    __builtin_amdgcn_global_load_lds(
        (const __attribute__((address_space(1))) u32*)gp,
        (__attribute__((address_space(3))) u32*)lp, 16, 0, 0);
}

#define PH_BAR()    __builtin_amdgcn_s_barrier()
#define LGKM0()     asm volatile("s_waitcnt lgkmcnt(0)" ::: "memory")
#define VMCNT3()    asm volatile("s_waitcnt vmcnt(3)" ::: "memory")
#define VMCNT0()    asm volatile("s_waitcnt vmcnt(0)" ::: "memory")

// ---------------- gating: softmax(x @ Wg + bg) -> g [N_TOK][NE] (f32) -----------
__global__ void gate_kernel(const float* __restrict__ x, const float* __restrict__ Wg,
                            const float* __restrict__ bg, float* __restrict__ g) {
    int w = threadIdx.x >> 6, lane = threadIdx.x & 63;
    int n = blockIdx.x * 4 + w;
    const float* xr = x + (size_t)n * DIN;
    float p[NE];
#pragma unroll
    for (int e = 0; e < NE; ++e) p[e] = 0.f;
    for (int i = lane; i < DIN; i += 64) {
        float xv = xr[i];
        const float* wr_ = Wg + i * NE;
#pragma unroll
        for (int e = 0; e < NE; ++e) p[e] = fmaf(xv, wr_[e], p[e]);
    }
#pragma unroll
    for (int off = 32; off > 0; off >>= 1) {
#pragma unroll
        for (int e = 0; e < NE; ++e) p[e] += __shfl_down(p[e], off);
    }
    if (lane == 0) {
        float l2[NE], m = -1e30f;
#pragma unroll
        for (int e = 0; e < NE; ++e) { l2[e] = p[e] + bg[e]; m = fmaxf(m, l2[e]); }
        float s = 0.f;
#pragma unroll
        for (int e = 0; e < NE; ++e) { l2[e] = expf(l2[e] - m); s += l2[e]; }
        float inv = 1.f / s;
#pragma unroll
        for (int e = 0; e < NE; ++e) g[n * NE + e] = l2[e] * inv;
    }
}

// ---------------- x (f32) -> xb (bf16) ------------------------------------------
__global__ void cvt_x_kernel(const float* __restrict__ x, ushort* __restrict__ xb) {
    int idx = blockIdx.x * 256 + threadIdx.x;
    float4 v = ((const float4*)x)[idx];
    ushort4 o = make_ushort4(f2bf(v.x), f2bf(v.y), f2bf(v.z), f2bf(v.w));
    ((ushort4*)xb)[idx] = o;
}

// ---------------- We [8192][1024] f32 -> BT [1024][8192] bf16 (transposed) ------
__global__ void transpose_w_kernel(const float* __restrict__ We, ushort* __restrict__ BT) {
    __shared__ float tile[64][65];
    int kb = blockIdx.x * 64, ob = blockIdx.y * 64;
    int t = threadIdx.x;
#pragma unroll
    for (int ph = 0; ph < 16; ++ph) {
        int idx = ph * 256 + t;
        int r = idx >> 6, c = idx & 63;
        tile[r][c] = We[(size_t)(kb + r) * DOUT + ob + c];
    }
    __syncthreads();
#pragma unroll
    for (int ph = 0; ph < 16; ++ph) {
        int idx = ph * 256 + t;
        int r = idx >> 6, c = idx & 63;
        BT[(size_t)(ob + r) * KTOT + kb + c] = f2bf(tile[c][r]);
    }
}

// ---------------- fused MoE GEMM, 8-phase counted-vmcnt schedule -----------------
// LDS layout per operand: [dbuf][khalf][rows * 32k], XOR-swizzled at 16B granularity:
//   linear LDS chunk (row, slot) holds global k-elems starting at (slot*8)^((row&6)<<2).
// Read of row r, k-group g -> LDS slot g^((r&6)>>1): quarter-wave bank-conflict-free.
__global__ __launch_bounds__(512, 2) void moe_gemm(
    const ushort* __restrict__ xb,   // [8192][1024] bf16
    const ushort* __restrict__ BT,   // [1024][8192] bf16 (o-major, k-minor)
    const float*  __restrict__ g,    // [8192][8]
    const float*  __restrict__ be,   // [8][1024]
    float*        __restrict__ out)  // [8192][1024]
{
    __shared__ __align__(16) ushort Al[2][2][BM * 32];   // 64 KB
    __shared__ __align__(16) ushort Bl[2][2][BN * 32];   // 32 KB
    __shared__ __align__(16) float  gLds[BM][NE];        //  8 KB

    int bid = blockIdx.x;
    // XCD swizzle (R1-proven structure): XCD x gets a contiguous row-slab.
    int swz = (bid & 7) * 32 + (bid >> 3);      // 256 blocks, 32 per XCD
    int colb = swz & 7;                          // 8 col blocks (1024/128)
    int rowb = swz >> 3;                         // 32 row blocks
    int brow = rowb * BM, bcol = colb * BN;

    int tid = threadIdx.x;
    int w = tid >> 6, lane = tid & 63;
    int wm = w >> 1, wn = w & 1;                 // 4x2 wave grid, 64x64 per wave
    int ro = lane & 15, gq = lane >> 4;
    int jrow = gq * 4;

    // gate probs -> LDS (so expert folds never touch VMEM mid-pipeline)
    float4 gv = ((const float4*)(g + (size_t)brow * NE))[tid];
    ((float4*)&gLds[0][0])[tid] = gv;

    // frag read offsets (elements, within a khalf buffer)
    int offA[4], offB[4];
#pragma unroll
    for (int m = 0; m < 4; ++m) {
        int r = wm * 64 + m * 16 + ro;
        offA[m] = r * 32 + ((gq * 8) ^ ((r & 6) << 2));
    }
#pragma unroll
    for (int n = 0; n < 4; ++n) {
        int c = wn * 64 + n * 16 + ro;
        offB[n] = c * 32 + ((gq * 8) ^ ((c & 6) << 2));
    }

    // staging: A-half = 2 loads/thread, B-half = 1 load/thread, source pre-swizzled
    auto stA = [&](int buf, int h, int t) {
#pragma unroll
        for (int L = 0; L < 2; ++L) {
            int chunk = L * 512 + tid;
            int row = chunk >> 2, slot = chunk & 3;
            int ks = (slot * 8) ^ ((row & 6) << 2);
            int ka = (t * BK + h * 32) & (DIN - 1);   // expert-local k for A
            gload_lds16(xb + (size_t)(brow + row) * DIN + ka + ks,
                        (char*)&Al[buf][h][0] + (size_t)(chunk & ~63) * 16);
        }
    };
    auto stB = [&](int buf, int h, int t) {
        int chunk = tid;
        int row = chunk >> 2, slot = chunk & 3;
        int ks = (slot * 8) ^ ((row & 6) << 2);
        int kg = t * BK + h * 32;
        gload_lds16(BT + (size_t)(bcol + row) * KTOT + kg + ks,
                    (char*)&Bl[buf][h][0] + (size_t)(chunk & ~63) * 16);
    };

    f32x4 accP[4][4];
    u32   accB[4][4][2];
#pragma unroll
    for (int m = 0; m < 4; ++m)
#pragma unroll
        for (int n = 0; n < 4; ++n) {
            accP[m][n] = (f32x4){0.f, 0.f, 0.f, 0.f};
            accB[m][n][0] = 0u; accB[m][n][1] = 0u;
        }

    // prologue: stage tile 0 (issue order: A0,A0,B0,A1,A1,B1), wait h0, barrier
    stA(0, 0, 0); stB(0, 0, 0); stA(0, 1, 0); stB(0, 1, 0);
    VMCNT3();        // A0,B0 done; A1x2,B1 in flight
    PH_BAR();

#define MFMA_PAIR(m, bl, br, n0, n1) \
    accP[m][n0] = __builtin_amdgcn_mfma_f32_16x16x32_bf16(a[m], bl, accP[m][n0], 0, 0, 0); \
    accP[m][n1] = __builtin_amdgcn_mfma_f32_16x16x32_bf16(a[m], br, accP[m][n1], 0, 0, 0);

    for (int t = 0; t < NT - 1; ++t) {
        int cur = t & 1, nxt = cur ^ 1;
        const ushort* A0 = &Al[cur][0][0];
        const ushort* A1 = &Al[cur][1][0];
        const ushort* B0 = &Bl[cur][0][0];
        const ushort* B1 = &Bl[cur][1][0];
        short8 a[4], b0, b1, b2, b3;

        // ---- phase 1: khalf0, n0-1 ----
#pragma unroll
        for (int m = 0; m < 4; ++m) a[m] = *(const short8*)(A0 + offA[m]);
        b0 = *(const short8*)(B0 + offB[0]);
        b1 = *(const short8*)(B0 + offB[1]);
        stA(nxt, 0, t + 1);
        PH_BAR(); LGKM0();
        __builtin_amdgcn_s_setprio(1);
#pragma unroll
        for (int m = 0; m < 4; ++m) { MFMA_PAIR(m, b0, b1, 0, 1) }
        __builtin_amdgcn_s_setprio(0);
        PH_BAR();

        // ---- phase 2: khalf0, n2-3 ----
        b2 = *(const short8*)(B0 + offB[2]);
        b3 = *(const short8*)(B0 + offB[3]);
        stB(nxt, 0, t + 1);
        PH_BAR(); LGKM0();
        __builtin_amdgcn_s_setprio(1);
#pragma unroll
        for (int m = 0; m < 4; ++m) { MFMA_PAIR(m, b2, b3, 2, 3) }
        __builtin_amdgcn_s_setprio(0);
        VMCNT3();    // A1(t),B1(t) done; A0(t+1)x2,B0(t+1) in flight
        PH_BAR();

        // ---- phase 3: khalf1, n0-1 ----
#pragma unroll
        for (int m = 0; m < 4; ++m) a[m] = *(const short8*)(A1 + offA[m]);
        b0 = *(const short8*)(B1 + offB[0]);
        b1 = *(const short8*)(B1 + offB[1]);
        stA(nxt, 1, t + 1);
        PH_BAR(); LGKM0();
        __builtin_amdgcn_s_setprio(1);
#pragma unroll
        for (int m = 0; m < 4; ++m) { MFMA_PAIR(m, b0, b1, 0, 1) }
        __builtin_amdgcn_s_setprio(0);
        PH_BAR();

        // ---- phase 4: khalf1, n2-3 ----
        b2 = *(const short8*)(B1 + offB[2]);
        b3 = *(const short8*)(B1 + offB[3]);
        stB(nxt, 1, t + 1);
        PH_BAR(); LGKM0();
        __builtin_amdgcn_s_setprio(1);
#pragma unroll
        for (int m = 0; m < 4; ++m) { MFMA_PAIR(m, b2, b3, 2, 3) }
        __builtin_amdgcn_s_setprio(0);

        // expert boundary (e = 0..6): fold gate-weighted partial into bf16 accB
        if ((t & 15) == 15) {
            int e = t >> 4;
#pragma unroll
            for (int m = 0; m < 4; ++m) {
                int rbase = wm * 64 + m * 16 + jrow;
                float g0 = gLds[rbase + 0][e], g1 = gLds[rbase + 1][e];
                float g2 = gLds[rbase + 2][e], g3 = gLds[rbase + 3][e];
#pragma unroll
                for (int n = 0; n < 4; ++n) {
                    u32 p0 = accB[m][n][0];
                    float lo0 = __uint_as_float(p0 << 16)         + g0 * accP[m][n][0];
                    float hi0 = __uint_as_float(p0 & 0xffff0000u) + g1 * accP[m][n][1];
                    accB[m][n][0] = (u32)f2bf(lo0) | ((u32)f2bf(hi0) << 16);
                    u32 p1 = accB[m][n][1];
                    float lo1 = __uint_as_float(p1 << 16)         + g2 * accP[m][n][2];
                    float hi1 = __uint_as_float(p1 & 0xffff0000u) + g3 * accP[m][n][3];
                    accB[m][n][1] = (u32)f2bf(lo1) | ((u32)f2bf(hi1) << 16);
                    accP[m][n] = (f32x4){0.f, 0.f, 0.f, 0.f};
                }
            }
        }
        VMCNT3();    // A0(t+1),B0(t+1) done; A1(t+1)x2,B1(t+1) in flight
        PH_BAR();
    }

    // ---- peeled last tile (t = NT-1, cur = 1): no staging ----
    {
        const ushort* A0 = &Al[1][0][0];
        const ushort* A1 = &Al[1][1][0];
        const ushort* B0 = &Bl[1][0][0];
        const ushort* B1 = &Bl[1][1][0];
        short8 a[4], b0, b1, b2, b3;

#pragma unroll
        for (int m = 0; m < 4; ++m) a[m] = *(const short8*)(A0 + offA[m]);
        b0 = *(const short8*)(B0 + offB[0]);
        b1 = *(const short8*)(B0 + offB[1]);
        PH_BAR(); LGKM0();
#pragma unroll
        for (int m = 0; m < 4; ++m) { MFMA_PAIR(m, b0, b1, 0, 1) }
        PH_BAR();

        b2 = *(const short8*)(B0 + offB[2]);
        b3 = *(const short8*)(B0 + offB[3]);
        PH_BAR(); LGKM0();
#pragma unroll
        for (int m = 0; m < 4; ++m) { MFMA_PAIR(m, b2, b3, 2, 3) }
        VMCNT0();    // drain A1,B1 of last tile
        PH_BAR();

#pragma unroll
        for (int m = 0; m < 4; ++m) a[m] = *(const short8*)(A1 + offA[m]);
        b0 = *(const short8*)(B1 + offB[0]);
        b1 = *(const short8*)(B1 + offB[1]);
        PH_BAR(); LGKM0();
#pragma unroll
        for (int m = 0; m < 4; ++m) { MFMA_PAIR(m, b0, b1, 0, 1) }
        PH_BAR();

        b2 = *(const short8*)(B1 + offB[2]);
        b3 = *(const short8*)(B1 + offB[3]);
        LGKM0();
#pragma unroll
        for (int m = 0; m < 4; ++m) { MFMA_PAIR(m, b2, b3, 2, 3) }
    }
#undef MFMA_PAIR

    // epilogue: out = unpack(accB) + g7*accP + sum_e g_e*be_e
#pragma unroll
    for (int m = 0; m < 4; ++m) {
#pragma unroll
        for (int j = 0; j < 4; ++j) {
            int lrow = wm * 64 + m * 16 + jrow + j;
            int grow = brow + lrow;
            float g8[NE];
#pragma unroll
            for (int e = 0; e < NE; ++e) g8[e] = gLds[lrow][e];
#pragma unroll
            for (int n = 0; n < 4; ++n) {
                int col = bcol + wn * 64 + n * 16 + ro;
                float bias = 0.f;
#pragma unroll
                for (int e = 0; e < NE; ++e) bias = fmaf(g8[e], be[e * DOUT + col], bias);
                u32 p = accB[m][n][j >> 1];
                float base = __uint_as_float((j & 1) ? (p & 0xffff0000u) : (p << 16));
                out[(size_t)grow * DOUT + col] = base + g8[7] * accP[m][n][j] + bias;
            }
        }
    }
}

extern "C" void kernel_launch(void* const* d_in, const int* in_sizes, int n_in,
                              void* d_out, int out_size, void* d_ws, size_t ws_size,
                              hipStream_t stream) {
    const float* x  = (const float*)d_in[0];
    const float* We = (const float*)d_in[1];
    const float* be = (const float*)d_in[2];
    const float* Wg = (const float*)d_in[3];
    const float* bg = (const float*)d_in[4];
    float* out = (float*)d_out;

    char* ws = (char*)d_ws;
    float*  gbuf = (float*)ws;                                       // 256 KB
    ushort* xb   = (ushort*)(ws + (size_t)256 * 1024);               // 16 MB
    ushort* BT   = (ushort*)(ws + (size_t)256 * 1024 + (size_t)N_TOK * DIN * 2); // 16 MB

    gate_kernel<<<N_TOK / 4, 256, 0, stream>>>(x, Wg, bg, gbuf);
    cvt_x_kernel<<<(N_TOK * DIN / 4) / 256, 256, 0, stream>>>(x, xb);
    transpose_w_kernel<<<dim3(KTOT / 64, DOUT / 64), 256, 0, stream>>>(We, BT);
    moe_gemm<<<(N_TOK / BM) * (DOUT / BN), 512, 0, stream>>>(xb, BT, gbuf, be, out);
}

// Round 4
// 192.509 us; speedup vs baseline: 1.5370x; 1.2773x over previous
//
#include <hip/hip_runtime.h>
#include <hip/hip_bf16.h>

#define N_TOK 8192
#define DIN   1024
#define DOUT  1024
#define NE    8
#define KTOT  (NE * DIN)          // 8192
#define BM    256
#define BN    128
#define NKH   (KTOT / 32)         // 256 half-tiles (k=32 each)

typedef __attribute__((ext_vector_type(4))) float f32x4;
typedef __attribute__((ext_vector_type(8))) short short8;
typedef unsigned int u32;

__device__ __forceinline__ ushort f2bf(float f) {
    u32 u = __float_as_uint(f);
    u32 r = (u + 0x7fffu + ((u >> 16) & 1u)) >> 16;   // round-to-nearest-even
    return (ushort)r;
}

__device__ __forceinline__ void gload_lds16(const void* gp, void* lp) {
    __builtin_amdgcn_global_load_lds(
        (const __attribute__((address_space(1))) u32*)gp,
        (__attribute__((address_space(3))) u32*)lp, 16, 0, 0);
}

#define PH_BAR()    __builtin_amdgcn_s_barrier()
#define LGKM0()     asm volatile("s_waitcnt lgkmcnt(0)" ::: "memory")
#define VMCNT6()    asm volatile("s_waitcnt vmcnt(6)" ::: "memory")
#define VMCNT3()    asm volatile("s_waitcnt vmcnt(3)" ::: "memory")
#define VMCNT0()    asm volatile("s_waitcnt vmcnt(0)" ::: "memory")

// ---------------- gating: softmax(x @ Wg + bg) -> g [N_TOK][NE] (f32) -----------
__global__ void gate_kernel(const float* __restrict__ x, const float* __restrict__ Wg,
                            const float* __restrict__ bg, float* __restrict__ g) {
    int w = threadIdx.x >> 6, lane = threadIdx.x & 63;
    int n = blockIdx.x * 4 + w;
    const float* xr = x + (size_t)n * DIN;
    float p[NE];
#pragma unroll
    for (int e = 0; e < NE; ++e) p[e] = 0.f;
    for (int i = lane; i < DIN; i += 64) {
        float xv = xr[i];
        const float* wr_ = Wg + i * NE;
#pragma unroll
        for (int e = 0; e < NE; ++e) p[e] = fmaf(xv, wr_[e], p[e]);
    }
#pragma unroll
    for (int off = 32; off > 0; off >>= 1) {
#pragma unroll
        for (int e = 0; e < NE; ++e) p[e] += __shfl_down(p[e], off);
    }
    if (lane == 0) {
        float l2[NE], m = -1e30f;
#pragma unroll
        for (int e = 0; e < NE; ++e) { l2[e] = p[e] + bg[e]; m = fmaxf(m, l2[e]); }
        float s = 0.f;
#pragma unroll
        for (int e = 0; e < NE; ++e) { l2[e] = expf(l2[e] - m); s += l2[e]; }
        float inv = 1.f / s;
#pragma unroll
        for (int e = 0; e < NE; ++e) g[n * NE + e] = l2[e] * inv;
    }
}

// ---------------- x (f32) -> xb (bf16) ------------------------------------------
__global__ void cvt_x_kernel(const float* __restrict__ x, ushort* __restrict__ xb) {
    int idx = blockIdx.x * 256 + threadIdx.x;
    float4 v = ((const float4*)x)[idx];
    ushort4 o = make_ushort4(f2bf(v.x), f2bf(v.y), f2bf(v.z), f2bf(v.w));
    ((ushort4*)xb)[idx] = o;
}

// ---------------- We [8192][1024] f32 -> BT [1024][8192] bf16 (transposed) ------
__global__ void transpose_w_kernel(const float* __restrict__ We, ushort* __restrict__ BT) {
    __shared__ float tile[64][65];
    int kb = blockIdx.x * 64, ob = blockIdx.y * 64;
    int t = threadIdx.x;
#pragma unroll
    for (int ph = 0; ph < 16; ++ph) {
        int idx = ph * 256 + t;
        int r = idx >> 6, c = idx & 63;
        tile[r][c] = We[(size_t)(kb + r) * DOUT + ob + c];
    }
    __syncthreads();
#pragma unroll
    for (int ph = 0; ph < 16; ++ph) {
        int idx = ph * 256 + t;
        int r = idx >> 6, c = idx & 63;
        BT[(size_t)(ob + r) * KTOT + kb + c] = f2bf(tile[c][r]);
    }
}

// ---------------- fused MoE GEMM: ring-of-4 half-tiles, 1 phase per k-half -------
// Per phase (k = half-tile index, 32 k-elems): 8 ds_read_b128 + issue group k+3
// (3 gload_lds) + barrier + lgkm0 + 16 MFMA + counted vmcnt(6) + barrier.
// 3 groups in flight -> each load has ~3 phases to land.
__global__ __launch_bounds__(512, 2) void moe_gemm(
    const ushort* __restrict__ xb,   // [8192][1024] bf16
    const ushort* __restrict__ BT,   // [1024][8192] bf16 (o-major, k-minor)
    const float*  __restrict__ g,    // [8192][8]
    const float*  __restrict__ be,   // [8][1024]
    float*        __restrict__ out)  // [8192][1024]
{
    __shared__ __align__(16) ushort Al[4][BM * 32];   // 64 KB ring
    __shared__ __align__(16) ushort Bl[4][BN * 32];   // 32 KB ring
    __shared__ __align__(16) float  gLds[BM][NE];     //  8 KB

    int bid = blockIdx.x;
    // XCD swizzle (R1/R3-proven): XCD x gets a contiguous row-slab.
    int swz = (bid & 7) * 32 + (bid >> 3);      // 256 blocks, 32 per XCD
    int colb = swz & 7;
    int rowb = swz >> 3;
    int brow = rowb * BM, bcol = colb * BN;

    int tid = threadIdx.x;
    int w = tid >> 6, lane = tid & 63;
    int wm = w >> 1, wn = w & 1;                 // 4x2 wave grid, 64x64 per wave
    int ro = lane & 15, gq = lane >> 4;
    int jrow = gq * 4;

    // gate probs -> LDS (expert folds never touch VMEM mid-pipeline)
    float4 gv = ((const float4*)(g + (size_t)brow * NE))[tid];
    ((float4*)&gLds[0][0])[tid] = gv;

    // fragment read offsets (elements, within one half-tile buffer), T2-swizzled
    int offA[4], offB[4];
#pragma unroll
    for (int m = 0; m < 4; ++m) {
        int r = wm * 64 + m * 16 + ro;
        offA[m] = r * 32 + ((gq * 8) ^ ((r & 6) << 2));
    }
#pragma unroll
    for (int n = 0; n < 4; ++n) {
        int c = wn * 64 + n * 16 + ro;
        offB[n] = c * 32 + ((gq * 8) ^ ((c & 6) << 2));
    }

    // staging group K (half-tile index): A = 2 loads/thread, B = 1 load/thread,
    // global source pre-swizzled so linear LDS dest + swizzled read agree (m173).
    auto stA = [&](int s, int K) {
#pragma unroll
        for (int L = 0; L < 2; ++L) {
            int chunk = L * 512 + tid;
            int row = chunk >> 2, slot = chunk & 3;
            int ks = (slot * 8) ^ ((row & 6) << 2);
            int ka = (K * 32) & (DIN - 1);           // expert-local k for A
            gload_lds16(xb + (size_t)(brow + row) * DIN + ka + ks,
                        (char*)&Al[s][0] + (size_t)(chunk & ~63) * 16);
        }
    };
    auto stB = [&](int s, int K) {
        int chunk = tid;
        int row = chunk >> 2, slot = chunk & 3;
        int ks = (slot * 8) ^ ((row & 6) << 2);
        gload_lds16(BT + (size_t)(bcol + row) * KTOT + K * 32 + ks,
                    (char*)&Bl[s][0] + (size_t)(chunk & ~63) * 16);
    };

    f32x4 accP[4][4];
    u32   accB[4][4][2];
#pragma unroll
    for (int m = 0; m < 4; ++m)
#pragma unroll
        for (int n = 0; n < 4; ++n) {
            accP[m][n] = (f32x4){0.f, 0.f, 0.f, 0.f};
            accB[m][n][0] = 0u; accB[m][n][1] = 0u;
        }

    // expert-boundary fold: accB += g_e * accP (bf16-packed), reset accP
    auto fold = [&](int e) {
#pragma unroll
        for (int m = 0; m < 4; ++m) {
            int rbase = wm * 64 + m * 16 + jrow;
            float g0 = gLds[rbase + 0][e], g1 = gLds[rbase + 1][e];
            float g2 = gLds[rbase + 2][e], g3 = gLds[rbase + 3][e];
#pragma unroll
            for (int n = 0; n < 4; ++n) {
                u32 p0 = accB[m][n][0];
                float lo0 = __uint_as_float(p0 << 16)         + g0 * accP[m][n][0];
                float hi0 = __uint_as_float(p0 & 0xffff0000u) + g1 * accP[m][n][1];
                accB[m][n][0] = (u32)f2bf(lo0) | ((u32)f2bf(hi0) << 16);
                u32 p1 = accB[m][n][1];
                float lo1 = __uint_as_float(p1 << 16)         + g2 * accP[m][n][2];
                float hi1 = __uint_as_float(p1 & 0xffff0000u) + g3 * accP[m][n][3];
                accB[m][n][1] = (u32)f2bf(lo1) | ((u32)f2bf(hi1) << 16);
                accP[m][n] = (f32x4){0.f, 0.f, 0.f, 0.f};
            }
        }
    };

    // one phase: reads + optional staging + barrier + lgkm + 16 MFMA (+ fold)
    auto do_phase = [&](int k, bool issue) {
        const ushort* As = &Al[k & 3][0];
        const ushort* Bs = &Bl[k & 3][0];
        short8 a[4];
#pragma unroll
        for (int m = 0; m < 4; ++m) a[m] = *(const short8*)(As + offA[m]);
        short8 b0 = *(const short8*)(Bs + offB[0]);
        short8 b1 = *(const short8*)(Bs + offB[1]);
        short8 b2 = *(const short8*)(Bs + offB[2]);
        short8 b3 = *(const short8*)(Bs + offB[3]);
        if (issue) { stA((k + 3) & 3, k + 3); stB((k + 3) & 3, k + 3); }
        PH_BAR(); LGKM0();
        __builtin_amdgcn_s_setprio(1);
#pragma unroll
        for (int m = 0; m < 4; ++m) {
            accP[m][0] = __builtin_amdgcn_mfma_f32_16x16x32_bf16(a[m], b0, accP[m][0], 0, 0, 0);
            accP[m][1] = __builtin_amdgcn_mfma_f32_16x16x32_bf16(a[m], b1, accP[m][1], 0, 0, 0);
            accP[m][2] = __builtin_amdgcn_mfma_f32_16x16x32_bf16(a[m], b2, accP[m][2], 0, 0, 0);
            accP[m][3] = __builtin_amdgcn_mfma_f32_16x16x32_bf16(a[m], b3, accP[m][3], 0, 0, 0);
        }
        __builtin_amdgcn_s_setprio(0);
        if ((k & 31) == 31 && k != NKH - 1) fold(k >> 5);   // experts 0..6
    };

    // prologue: stage groups 0,1,2 (9 loads); wait group 0; barrier
    stA(0, 0); stB(0, 0);
    stA(1, 1); stB(1, 1);
    stA(2, 2); stB(2, 2);
    VMCNT6();
    PH_BAR();

    // main loop: phases 0 .. NKH-4, each issues group k+3
    for (int k = 0; k < NKH - 3; ++k) {
        do_phase(k, true);
        VMCNT6();          // group k+1 landed; k+2, k+3 in flight
        PH_BAR();
    }
    // tail: no more issues, drain the counted pipeline
    do_phase(NKH - 3, false); VMCNT3(); PH_BAR();
    do_phase(NKH - 2, false); VMCNT0(); PH_BAR();
    do_phase(NKH - 1, false);            // expert 7 stays in accP

    // epilogue: out = unpack(accB) + g7*accP + sum_e g_e*be_e
#pragma unroll
    for (int m = 0; m < 4; ++m) {
#pragma unroll
        for (int j = 0; j < 4; ++j) {
            int lrow = wm * 64 + m * 16 + jrow + j;
            int grow = brow + lrow;
            float g8[NE];
#pragma unroll
            for (int e = 0; e < NE; ++e) g8[e] = gLds[lrow][e];
#pragma unroll
            for (int n = 0; n < 4; ++n) {
                int col = bcol + wn * 64 + n * 16 + ro;
                float bias = 0.f;
#pragma unroll
                for (int e = 0; e < NE; ++e) bias = fmaf(g8[e], be[e * DOUT + col], bias);
                u32 p = accB[m][n][j >> 1];
                float base = __uint_as_float((j & 1) ? (p & 0xffff0000u) : (p << 16));
                out[(size_t)grow * DOUT + col] = base + g8[7] * accP[m][n][j] + bias;
            }
        }
    }
}

extern "C" void kernel_launch(void* const* d_in, const int* in_sizes, int n_in,
                              void* d_out, int out_size, void* d_ws, size_t ws_size,
                              hipStream_t stream) {
    const float* x  = (const float*)d_in[0];
    const float* We = (const float*)d_in[1];
    const float* be = (const float*)d_in[2];
    const float* Wg = (const float*)d_in[3];
    const float* bg = (const float*)d_in[4];
    float* out = (float*)d_out;

    char* ws = (char*)d_ws;
    float*  gbuf = (float*)ws;                                       // 256 KB
    ushort* xb   = (ushort*)(ws + (size_t)256 * 1024);               // 16 MB
    ushort* BT   = (ushort*)(ws + (size_t)256 * 1024 + (size_t)N_TOK * DIN * 2); // 16 MB

    gate_kernel<<<N_TOK / 4, 256, 0, stream>>>(x, Wg, bg, gbuf);
    cvt_x_kernel<<<(N_TOK * DIN / 4) / 256, 256, 0, stream>>>(x, xb);
    transpose_w_kernel<<<dim3(KTOT / 64, DOUT / 64), 256, 0, stream>>>(We, BT);
    moe_gemm<<<(N_TOK / BM) * (DOUT / BN), 512, 0, stream>>>(xb, BT, gbuf, be, out);
}